// Round 20
// baseline (157.556 us; speedup 1.0000x reference)
//
#include <hip/hip_runtime.h>
#include <math.h>

#define NEMB 512
#define LAT 32

typedef unsigned short u16;
typedef unsigned int u32;
typedef __attribute__((ext_vector_type(8))) short bf16x8;   // 8 bf16 in 4 VGPRs
typedef __attribute__((ext_vector_type(4))) float f32x4;

__device__ __forceinline__ u16 f2b(float f) {               // fp32 -> bf16 RTNE
    unsigned u = __builtin_bit_cast(unsigned, f);
    return (u16)((u + 0x7fffu + ((u >> 16) & 1u)) >> 16);
}
__device__ __forceinline__ float b2f(u16 h) {
    unsigned u = ((unsigned)h) << 16;
    return __builtin_bit_cast(float, u);
}
// packed bf16-pair dot product: acc += a.lo*b.lo + a.hi*b.hi  (full-rate VALU)
__device__ __forceinline__ void dot2(float& acc, u32 a, u32 b) {
    asm("v_dot2_f32_bf16 %0, %1, %2, %0" : "+v"(acc) : "v"(a), "v"(b));
}

union V16 { uint4 u; u16 s[8]; };
union V8  { uint2 u; u16 s[4]; };

// ---------------- workspace layout (BYTES); ws >= 109 MB (round-1 proven) ----
static const size_t OFF_H1  = 0;          // h1 [128,64,64,32] bf16 (later g2)
static const size_t OFF_H2  = 33554432;   // h2 [128,32,32,64] bf16 (later g1)
static const size_t OFF_ZQ  = 52428800;   // zq [128,16,16,32] bf16
static const size_t OFF_W2T = 54525952;   // [16][64][32] bf16
static const size_t OFF_W3T = 54591488;   // [16][32][64] bf16
static const size_t OFF_D1T = 54657024;   // [16][64][32] bf16
static const size_t OFF_D2T = 54722560;   // [16][32][64] bf16
static const size_t OFF_ACC = 54804480;   // f32: [0..255] recon buckets, [256..511] vq buckets
static const size_t OFF_E2  = 54808576;   // f32: per-code ||e||^2 (512 f)
static const size_t OFF_W1T = 54810624;   // [2][32co][32k] bf16 (4 KB)
static const size_t OFF_XB  = 54814720;   // xb [128][130][130][4] bf16 (17.3 MB)
static const size_t OFF_D3P = 72120320;   // u32 [16cp][3co][16kykx] packed pairs (3 KB)

// =================================================================
// prep + xb in ONE dispatch (blocks [0,528) transforms, rest xb)
// =================================================================
__global__ __launch_bounds__(256)
void prep_xb(const float* __restrict__ w2, const float* __restrict__ w3,
             const float* __restrict__ d1, const float* __restrict__ d2,
             const float* __restrict__ d3, const float* __restrict__ emb,
             const float* __restrict__ w1, const float* __restrict__ x,
             u16* __restrict__ w2t, u16* __restrict__ w3t, u16* __restrict__ d1t,
             u16* __restrict__ d2t, u32* __restrict__ d3p, u16* __restrict__ w1t,
             u16* __restrict__ xb,
             float* __restrict__ accum, float* __restrict__ e2) {
    if (blockIdx.x >= 528) {
        int t = (blockIdx.x - 528) * 256 + threadIdx.x;   // 128*130*130
        int xx = t % 130; int t2 = t / 130;
        int yy = t2 % 130; int n = t2 / 130;
        V8 o; o.u = (uint2){0, 0};
        if (xx >= 1 && xx <= 128 && yy >= 1 && yy <= 128) {
            size_t base = ((size_t)n * 3) * 16384 + (size_t)(yy - 1) * 128 + (xx - 1);
            o.s[0] = f2b(x[base]);
            o.s[1] = f2b(x[base + 16384]);
            o.s[2] = f2b(x[base + 32768]);
        }
        *(uint2*)&xb[(size_t)t * 4] = o.u;
        return;
    }
    int t = blockIdx.x * 256 + threadIdx.x;
    if (t < 32768) {                       // w2: conv, CO=64 CI=32 -> [tau][co][ci]
        int ci = t & 31; int t2 = t >> 5; int co = t2 & 63; int tau = t2 >> 6;
        w2t[t] = f2b(w2[((size_t)co * 32 + ci) * 16 + tau]);
    } else if (t < 65536) {                // w3: conv, CO=32 CI=64
        int u = t - 32768;
        int ci = u & 63; int t2 = u >> 6; int co = t2 & 31; int tau = t2 >> 5;
        w3t[u] = f2b(w3[((size_t)co * 64 + ci) * 16 + tau]);
    } else if (t < 98304) {                // d1: deconv, CO=64 CI=32 -> [s][co][ci]
        int u = t - 65536;
        int ci = u & 31; int t2 = u >> 5; int co = t2 & 63; int s = t2 >> 6;
        int ry = (s >> 3) & 1, rx = (s >> 2) & 1, a = (s >> 1) & 1, b = s & 1;
        int ky = ((ry + 1) & 1) + 2 * a, kx = ((rx + 1) & 1) + 2 * b;
        d1t[u] = f2b(d1[((size_t)ci * 64 + co) * 16 + ky * 4 + kx]);
    } else if (t < 131072) {               // d2: deconv, CO=32 CI=64
        int u = t - 98304;
        int ci = u & 63; int t2 = u >> 6; int co = t2 & 31; int s = t2 >> 5;
        int ry = (s >> 3) & 1, rx = (s >> 2) & 1, a = (s >> 1) & 1, b = s & 1;
        int ky = ((ry + 1) & 1) + 2 * a, kx = ((rx + 1) & 1) + 2 * b;
        d2t[u] = f2b(d2[((size_t)ci * 32 + co) * 16 + ky * 4 + kx]);
    } else if (t < 131584) {               // e2
        int u = t - 131072;
        float s = 0.f;
        #pragma unroll
        for (int c = 0; c < LAT; ++c) { float e = emb[u * LAT + c]; s = fmaf(e, e, s); }
        e2[u] = s;
    } else if (t < 132096) {               // zero accumulators
        accum[t - 131584] = 0.f;
    } else if (t < 134144) {               // w1t: [2][32co][32k]
        int u = t - 132096;
        int k = u & 31; int co = (u >> 5) & 31; int c = u >> 10;
        int kyl = k >> 4, kx = (k >> 2) & 3, ch = k & 3;
        w1t[u] = (ch < 3) ? f2b(w1[((size_t)(co * 3 + ch) * 4 + (2 * c + kyl)) * 4 + kx])
                          : (u16)0;
    } else if (t < 134912) {               // d3p: packed ci-pair weights [cp][co][kykx]
        int u = t - 134144;                // 0..767
        int kk = u & 15; int t2 = u >> 4;
        int co = t2 % 3; int cp = t2 / 3;
        u16 lo = f2b(d3[((size_t)(2 * cp) * 3 + co) * 16 + kk]);
        u16 hi = f2b(d3[((size_t)(2 * cp + 1) * 3 + co) * 16 + kk]);
        d3p[u] = (u32)lo | ((u32)hi << 16);
    }
}

// =================================================================
// conv1 MFMA: implicit GEMM, K=64, no LDS, no barrier.
// =================================================================
__global__ __launch_bounds__(256)
void conv1_mfma(const u16* __restrict__ xb, const u16* __restrict__ w1t,
                const float* __restrict__ b1, u16* __restrict__ h1) {
    int bid = blockIdx.x;                       // 128 n x 16 oyb
    const int oyb = bid & 15; const int n = bid >> 4;
    const int tid = threadIdx.x, w = tid >> 6, lane = tid & 63;
    const int l15 = lane & 15, l4 = lane >> 4;
    const int oy = oyb * 4 + w;

    bf16x8 bf[2][2];
    #pragma unroll
    for (int c = 0; c < 2; ++c)
        #pragma unroll
        for (int cf = 0; cf < 2; ++cf)
            bf[c][cf] = *(const bf16x8*)&w1t[((size_t)(c * 32 + cf * 16 + l15)) * 32 + l4 * 8];

    f32x4 acc[4][2];
    #pragma unroll
    for (int f = 0; f < 4; ++f)
        #pragma unroll
        for (int cf = 0; cf < 2; ++cf) {
            float bv = b1[cf * 16 + l15];
            acc[f][cf] = (f32x4){bv, bv, bv, bv};
        }

    #pragma unroll
    for (int c = 0; c < 2; ++c) {
        const int row = 2 * oy + 2 * c + (l4 >> 1);
        #pragma unroll
        for (int f = 0; f < 4; ++f) {
            const int col = 2 * (f * 16 + l15) + (l4 & 1) * 2;
            bf16x8 a = *(const bf16x8*)&xb[(((size_t)n * 130 + row) * 130 + col) * 4];
            acc[f][0] = __builtin_amdgcn_mfma_f32_16x16x32_bf16(a, bf[c][0], acc[f][0], 0, 0, 0);
            acc[f][1] = __builtin_amdgcn_mfma_f32_16x16x32_bf16(a, bf[c][1], acc[f][1], 0, 0, 0);
        }
    }

    #pragma unroll
    for (int f = 0; f < 4; ++f)
        #pragma unroll
        for (int cf = 0; cf < 2; ++cf)
            #pragma unroll
            for (int rg = 0; rg < 4; ++rg) {
                int ox = f * 16 + l4 * 4 + rg;
                h1[(((size_t)n * 64 + oy) * 64 + ox) * 32 + cf * 16 + l15] =
                    f2b(fmaxf(acc[f][cf][rg], 0.f));
            }
}

// =================================================================
// MFMA conv k4s2 (conv2): NHWC bf16 in/out.
// =================================================================
template <int CI, int CO, int HI, int WI, bool RELU>
__global__ __launch_bounds__(256)
void mfma_conv(const u16* __restrict__ xin, const u16* __restrict__ wt,
               const float* __restrict__ bias, u16* __restrict__ out) {
    constexpr int HO = HI / 2, WO = WI / 2;
    constexpr int BCOLS = (WO < 32) ? WO : 32;
    constexpr int XC = 2 * BCOLS + 2;
    constexpr int NCOLF = BCOLS / 16, NCOF = CO / 16, NCC = CI / 32;
    constexpr int CPU8 = CI / 8;
    __shared__ u16 sx[10 * XC * CI];

    int bid = blockIdx.x;
    constexpr int NBY = HO / 4, NTX = WO / BCOLS;
    const int tx = bid % NTX; bid /= NTX;
    const int by = bid % NBY; const int n = bid / NBY;
    const int oy0 = by * 4, ox0 = tx * BCOLS;
    const int tid = threadIdx.x, w = tid >> 6, lane = tid & 63;
    const int l15 = lane & 15, l4 = lane >> 4;

    const int iyb = 2 * oy0 - 1, ixb = 2 * ox0 - 1;
    for (int u = tid; u < 10 * XC * CPU8; u += 256) {
        int c8 = u % CPU8; int t2 = u / CPU8;
        int xc = t2 % XC; int r = t2 / XC;
        int iy = iyb + r, ix = ixb + xc;
        uint4 v = {0, 0, 0, 0};
        if (iy >= 0 && iy < HI && ix >= 0 && ix < WI)
            v = *(const uint4*)&xin[(((size_t)n * HI + iy) * WI + ix) * CI + c8 * 8];
        int byte = ((r * XC + xc) * CI + c8 * 8) * 2;
        byte ^= ((xc >> 1) & 7) << 4;
        *(uint4*)&sx[byte >> 1] = v;
    }
    __syncthreads();

    f32x4 acc[NCOLF][NCOF];
    #pragma unroll
    for (int pf = 0; pf < NCOLF; ++pf)
        #pragma unroll
        for (int cf = 0; cf < NCOF; ++cf) {
            float bv = bias[cf * 16 + l15];
            acc[pf][cf] = (f32x4){bv, bv, bv, bv};
        }

    #pragma unroll 4
    for (int tau = 0; tau < 16; ++tau) {
        const int ky = tau >> 2, kx = tau & 3;
        const int r = 2 * w + ky;
        #pragma unroll
        for (int cc = 0; cc < NCC; ++cc) {
            bf16x8 b[NCOF];
            #pragma unroll
            for (int cf = 0; cf < NCOF; ++cf)
                b[cf] = *(const bf16x8*)&wt[((size_t)(tau * CO + cf * 16 + l15)) * CI + cc * 32 + l4 * 8];
            bf16x8 a[NCOLF];
            #pragma unroll
            for (int pf = 0; pf < NCOLF; ++pf) {
                int xc = 2 * (pf * 16 + l15) + kx;
                int byte = ((r * XC + xc) * CI + cc * 32 + l4 * 8) * 2;
                byte ^= ((xc >> 1) & 7) << 4;
                a[pf] = *(const bf16x8*)&sx[byte >> 1];
            }
            #pragma unroll
            for (int pf = 0; pf < NCOLF; ++pf)
                #pragma unroll
                for (int cf = 0; cf < NCOF; ++cf)
                    acc[pf][cf] = __builtin_amdgcn_mfma_f32_16x16x32_bf16(
                        a[pf], b[cf], acc[pf][cf], 0, 0, 0);
        }
    }

    const int oy = oy0 + w;
    #pragma unroll
    for (int pf = 0; pf < NCOLF; ++pf)
        #pragma unroll
        for (int cf = 0; cf < NCOF; ++cf)
            #pragma unroll
            for (int rg = 0; rg < 4; ++rg) {
                int ox = ox0 + pf * 16 + l4 * 4 + rg;
                float v = acc[pf][cf][rg];
                if (RELU) v = fmaxf(v, 0.f);
                out[(((size_t)n * HO + oy) * WO + ox) * CO + cf * 16 + l15] = f2b(v);
            }
}

// =================================================================
// conv3 + FUSED VQ: conv (CI=64,CO=32,32x32->16x16) computes the block's
// 64 z-vectors; sx LDS is then reused for the swizzled codebook + z-tile,
// and each wave runs the (verified) MFMA-VQ on its 16 vectors. No global z.
// =================================================================
__global__ __launch_bounds__(256)
void conv3_vq(const u16* __restrict__ xin, const u16* __restrict__ wt,
              const float* __restrict__ bias, const float* __restrict__ emb,
              const float* __restrict__ e2g, u16* __restrict__ zq,
              float* __restrict__ vq_buckets) {
    __shared__ char smem[43520];               // 43.5 KB (same as plain conv3)
    u16*   sx   = (u16*)smem;                  // phase 1: 10*34*64 u16
    u16*   semb = (u16*)smem;                  // phase 2: 32 KB codebook (swizzled)
    float* se2  = (float*)(smem + 32768);      // 2 KB
    u16*   zt   = (u16*)(smem + 34816);        // [64 pix][40] u16 (5 KB)

    int bid = blockIdx.x;                      // 512 = 128 n x 4 by
    const int by = bid & 3; const int n = bid >> 2;
    const int oy0 = by * 4;
    const int tid = threadIdx.x, w = tid >> 6, lane = tid & 63;
    const int l15 = lane & 15, l4 = lane >> 4;

    // ---- phase 1: conv staging ----
    const int iyb = 2 * oy0 - 1;
    for (int u = tid; u < 10 * 34 * 8; u += 256) {
        int c8 = u % 8; int t2 = u / 8;
        int xc = t2 % 34; int r = t2 / 34;
        int iy = iyb + r, ix = xc - 1;
        uint4 v = {0, 0, 0, 0};
        if (iy >= 0 && iy < 32 && ix >= 0 && ix < 32)
            v = *(const uint4*)&xin[(((size_t)n * 32 + iy) * 32 + ix) * 64 + c8 * 8];
        int byte = ((r * 34 + xc) * 64 + c8 * 8) * 2;
        byte ^= ((xc >> 1) & 7) << 4;
        *(uint4*)&sx[byte >> 1] = v;
    }
    __syncthreads();

    f32x4 acc[2];
    #pragma unroll
    for (int cf = 0; cf < 2; ++cf) {
        float bv = bias[cf * 16 + l15];
        acc[cf] = (f32x4){bv, bv, bv, bv};
    }

    #pragma unroll 4
    for (int tau = 0; tau < 16; ++tau) {
        const int ky = tau >> 2, kx = tau & 3;
        const int r = 2 * w + ky;
        #pragma unroll
        for (int cc = 0; cc < 2; ++cc) {
            bf16x8 b[2];
            #pragma unroll
            for (int cf = 0; cf < 2; ++cf)
                b[cf] = *(const bf16x8*)&wt[((size_t)(tau * 32 + cf * 16 + l15)) * 64 + cc * 32 + l4 * 8];
            int xc = 2 * l15 + kx;
            int byte = ((r * 34 + xc) * 64 + cc * 32 + l4 * 8) * 2;
            byte ^= ((xc >> 1) & 7) << 4;
            bf16x8 a = *(const bf16x8*)&sx[byte >> 1];
            acc[0] = __builtin_amdgcn_mfma_f32_16x16x32_bf16(a, b[0], acc[0], 0, 0, 0);
            acc[1] = __builtin_amdgcn_mfma_f32_16x16x32_bf16(a, b[1], acc[1], 0, 0, 0);
        }
    }
    __syncthreads();   // all waves done reading sx

    // ---- phase 2: stage codebook (reuses sx space) + deposit z-tile ----
    for (int u = tid; u < 2048; u += 256) {
        int code = u >> 2, seg = u & 3;
        const float4* ep = (const float4*)&emb[code * 32 + seg * 8];
        float4 e0 = ep[0], e1 = ep[1];
        V16 o;
        o.s[0] = f2b(e0.x); o.s[1] = f2b(e0.y); o.s[2] = f2b(e0.z); o.s[3] = f2b(e0.w);
        o.s[4] = f2b(e1.x); o.s[5] = f2b(e1.y); o.s[6] = f2b(e1.z); o.s[7] = f2b(e1.w);
        int byte = (code * 64 + seg * 16) ^ ((code & 7) << 4);
        *(uint4*)((char*)semb + byte) = o.u;
    }
    for (int u = tid; u < NEMB; u += 256) se2[u] = e2g[u];
    #pragma unroll
    for (int cf = 0; cf < 2; ++cf)
        #pragma unroll
        for (int rg = 0; rg < 4; ++rg)
            zt[(w * 16 + l4 * 4 + rg) * 40 + cf * 16 + l15] = f2b(acc[cf][rg]);
    __syncthreads();

    // ---- phase 3: VQ (verified vq_mfma body; A from zt) ----
    bf16x8 a = *(const bf16x8*)&zt[(w * 16 + l15) * 40 + l4 * 8];

    float best[4] = {1e30f, 1e30f, 1e30f, 1e30f};
    int   bidx[4] = {0, 0, 0, 0};
    #pragma unroll
    for (int f = 0; f < 32; ++f) {
        int byteb = ((f * 16 + l15) * 64 + l4 * 16) ^ ((l15 & 7) << 4);
        bf16x8 bfrag = *(const bf16x8*)((const char*)semb + byteb);
        f32x4 s = {0.f, 0.f, 0.f, 0.f};
        s = __builtin_amdgcn_mfma_f32_16x16x32_bf16(a, bfrag, s, 0, 0, 0);
        float e2c = se2[f * 16 + l15];
        int cidx = f * 16 + l15;
        #pragma unroll
        for (int j = 0; j < 4; ++j) {
            float d = fmaf(s[j], -2.f, e2c);
            bool lt = d < best[j];               // strict <: first-index tie rule
            best[j] = lt ? d : best[j];
            bidx[j] = lt ? cidx : bidx[j];
        }
    }
    #pragma unroll
    for (int m = 1; m < 16; m <<= 1) {
        #pragma unroll
        for (int j = 0; j < 4; ++j) {
            float ob = __shfl_xor(best[j], m, 64);
            int   oi = __shfl_xor(bidx[j], m, 64);
            bool take = (ob < best[j]) || (ob == best[j] && oi < bidx[j]);
            best[j] = take ? ob : best[j];
            bidx[j] = take ? oi : bidx[j];
        }
    }
    const int r = lane >> 2;                     // local pixel within wave
    const int j0 = r & 3;
    int k = (j0 == 0) ? bidx[0] : (j0 == 1) ? bidx[1] : (j0 == 2) ? bidx[2] : bidx[3];
    const int seg = lane & 3;
    const float4* ep = (const float4*)&emb[k * LAT + seg * 8];
    float4 e0 = ep[0], e1 = ep[1];
    float ev[8] = {e0.x, e0.y, e0.z, e0.w, e1.x, e1.y, e1.z, e1.w};
    V16 zr; zr.u = *(const uint4*)&zt[(w * 16 + r) * 40 + seg * 8];
    size_t zoff = ((size_t)n * 256 + (size_t)(oy0 + w) * 16 + r) * LAT + seg * 8;
    V16 o;
    float local = 0.f;
    #pragma unroll
    for (int jj = 0; jj < 8; ++jj) {
        float dd = ev[jj] - b2f(zr.s[jj]);
        local = fmaf(dd, dd, local);
        o.s[jj] = f2b(ev[jj]);
    }
    *(uint4*)&zq[zoff] = o.u;
    #pragma unroll
    for (int off = 32; off; off >>= 1) local += __shfl_down(local, off, 64);
    if (lane == 0) atomicAdd(&vq_buckets[blockIdx.x & 255], local);
}

// =================================================================
// MFMA deconv k4s2, ry = blockIdx.y, WEIGHTS IN LDS (proven r13).
// relu -> bf16 NHWC.
// =================================================================
template <int CI, int CO, int HI, int WI>
__global__ __launch_bounds__(256)
void mfma_deconv_wl(const u16* __restrict__ xin, const u16* __restrict__ wt,
                    const float* __restrict__ bias, u16* __restrict__ out) {
    constexpr int HO = 2 * HI, WO = 2 * WI;
    constexpr int BCOLS = (WI < 32) ? WI : 32;
    constexpr int XC = BCOLS + 2;
    constexpr int NCOLF = BCOLS / 16, NCOF = CO / 16, NCC = CI / 32;
    constexpr int CPU8 = CI / 8;
    __shared__ u16 sx[5 * XC * CI];
    __shared__ u16 swt[8 * CO * CI];          // 32 KB

    const int ry = blockIdx.y;
    int bid = blockIdx.x;
    constexpr int NBY = HI / 4, NTX = WI / BCOLS;
    const int tx = bid % NTX; bid /= NTX;
    const int by = bid % NBY; const int n = bid / NBY;
    const int q0 = by * 4, r0 = tx * BCOLS;
    const int tid = threadIdx.x, w = tid >> 6, lane = tid & 63;
    const int l15 = lane & 15, l4 = lane >> 4;

    const int qb = q0 + ry - 1;
    for (int u = tid; u < 5 * XC * CPU8; u += 256) {
        int c8 = u % CPU8; int t2 = u / CPU8;
        int xc = t2 % XC; int r = t2 / XC;
        int iy = qb + r, ix = r0 - 1 + xc;
        uint4 v = {0, 0, 0, 0};
        if (iy >= 0 && iy < HI && ix >= 0 && ix < WI)
            v = *(const uint4*)&xin[(((size_t)n * HI + iy) * WI + ix) * CI + c8 * 8];
        int byte = ((r * XC + xc) * CI + c8 * 8) * 2;
        byte ^= (xc & 7) << 4;
        *(uint4*)&sx[byte >> 1] = v;
    }
    const u16* wts = wt + (size_t)(ry * 8) * CO * CI;
    for (int u = tid; u < 8 * CO * CPU8; u += 256) {
        int c8 = u % CPU8; int t2 = u / CPU8;
        int co = t2 % CO; int l = t2 / CO;
        uint4 v = *(const uint4*)&wts[((size_t)l * CO + co) * CI + c8 * 8];
        int byte = ((l * CO + co) * CI + c8 * 8) * 2;
        byte ^= (co & 7) << 4;
        *(uint4*)&swt[byte >> 1] = v;
    }
    __syncthreads();

    f32x4 acc[2][NCOLF][NCOF];
    #pragma unroll
    for (int rx = 0; rx < 2; ++rx)
        #pragma unroll
        for (int pf = 0; pf < NCOLF; ++pf)
            #pragma unroll
            for (int cf = 0; cf < NCOF; ++cf) {
                float bv = bias[cf * 16 + l15];
                acc[rx][pf][cf] = (f32x4){bv, bv, bv, bv};
            }

    #pragma unroll
    for (int rx = 0; rx < 2; ++rx) {
        #pragma unroll
        for (int tap = 0; tap < 4; ++tap) {
            const int a_ = tap >> 1, b_ = tap & 1;
            const int r = w + 1 - a_;
            const int l = rx * 4 + tap;
            #pragma unroll
            for (int cc = 0; cc < NCC; ++cc) {
                bf16x8 b[NCOF];
                #pragma unroll
                for (int cf = 0; cf < NCOF; ++cf) {
                    int co = cf * 16 + l15;
                    int byte = (((l * CO + co) * CI + cc * 32 + l4 * 8) * 2) ^ ((co & 7) << 4);
                    b[cf] = *(const bf16x8*)((const char*)swt + byte);
                }
                bf16x8 a[NCOLF];
                #pragma unroll
                for (int pf = 0; pf < NCOLF; ++pf) {
                    int xc = pf * 16 + l15 + rx - b_ + 1;
                    int byte = ((r * XC + xc) * CI + cc * 32 + l4 * 8) * 2;
                    byte ^= (xc & 7) << 4;
                    a[pf] = *(const bf16x8*)&sx[byte >> 1];
                }
                #pragma unroll
                for (int pf = 0; pf < NCOLF; ++pf)
                    #pragma unroll
                    for (int cf = 0; cf < NCOF; ++cf)
                        acc[rx][pf][cf] = __builtin_amdgcn_mfma_f32_16x16x32_bf16(
                            a[pf], b[cf], acc[rx][pf][cf], 0, 0, 0);
            }
        }
    }

    const int oy = 2 * (q0 + w) + ry;
    #pragma unroll
    for (int rx = 0; rx < 2; ++rx)
        #pragma unroll
        for (int pf = 0; pf < NCOLF; ++pf)
            #pragma unroll
            for (int cf = 0; cf < NCOF; ++cf)
                #pragma unroll
                for (int rg = 0; rg < 4; ++rg) {
                    int ox = 2 * (r0 + pf * 16 + l4 * 4 + rg) + rx;
                    float v = fmaxf(acc[rx][pf][cf][rg], 0.f);
                    out[(((size_t)n * HO + oy) * WO + ox) * CO + cf * 16 + l15] = f2b(v);
                }
}

// =================================================================
// deconv3 dot2 (r17 best): taps from LDS ci-pair planes; packed
// weights broadcast from a 3 KB LDS buffer. PPT=4, parity-grouped.
// =================================================================
__global__ __launch_bounds__(256)
void deconv3_dot2(const u16* __restrict__ g2, const u32* __restrict__ d3p,
                  const float* __restrict__ db3, float* __restrict__ out,
                  const float* __restrict__ ref, float* __restrict__ buckets) {
    __shared__ u32 sxp[16 * 412];         // 26.4 KB (16 ci-pair planes)
    __shared__ u32 sw[768];               // 3 KB packed weights [cp][co][kykx]
    int bid = blockIdx.x;
    const int ty = bid & 15; const int n = bid >> 4;
    const int tid = threadIdx.x;
    const int w = tid >> 6, lane = tid & 63;
    const int row = (w & 1) + 4 * (w >> 1) + 2 * (lane >> 5);   // parity-grouped
    const int cg = lane & 31;                  // 32 col groups x 4 px

    const int iy_org = ty * 4 - 1;

    for (int u = tid; u < 6 * 66 * 4; u += 256) {
        int c8 = u & 3; int pos = u >> 2;
        int col = pos % 66; int r = pos / 66;
        int iy = iy_org + r, ix = col - 1;
        uint4 v = {0, 0, 0, 0};
        if (iy >= 0 && iy < 64 && ix >= 0 && ix < 64)
            v = *(const uint4*)&g2[(((size_t)n * 64 + iy) * 64 + ix) * 32 + c8 * 8];
        int base = r * 68 + col;
        sxp[(c8 * 4 + 0) * 412 + base] = v.x;
        sxp[(c8 * 4 + 1) * 412 + base] = v.y;
        sxp[(c8 * 4 + 2) * 412 + base] = v.z;
        sxp[(c8 * 4 + 3) * 412 + base] = v.w;
    }
    for (int l = tid; l < 768; l += 256) sw[l] = d3p[l];
    __syncthreads();

    const int ky0 = (row + 1) & 1;               // wave-uniform
    const int iyA = ((row + 1 - ky0) >> 1) + 1;
    const int iyB = iyA - 1;
    const int q = cg * 2;

    float acc[3][4];
    #pragma unroll
    for (int co = 0; co < 3; ++co) {
        float b = db3[co];
        #pragma unroll
        for (int p = 0; p < 4; ++p) acc[co][p] = b;
    }

    #pragma unroll 1
    for (int c2 = 0; c2 < 16; ++c2) {
        uint4 hA = *(const uint4*)&sxp[c2 * 412 + iyA * 68 + q];
        uint4 hB = *(const uint4*)&sxp[c2 * 412 + iyB * 68 + q];
        u32 ta[4] = {hA.x, hA.y, hA.z, hA.w};
        u32 tb[4] = {hB.x, hB.y, hB.z, hB.w};
        #pragma unroll
        for (int co = 0; co < 3; ++co) {
            uint4 wA = *(const uint4*)&sw[(c2 * 3 + co) * 16 + ky0 * 4];        // broadcast
            uint4 wB = *(const uint4*)&sw[(c2 * 3 + co) * 16 + (ky0 + 2) * 4];  // broadcast
            #pragma unroll
            for (int p = 0; p < 4; ++p) {
                const int A = (p + 3) >> 1;
                const int B = (p + 1) >> 1;
                if (((p + 1) & 1) == 1) {     // p even -> kx0 = 1
                    dot2(acc[co][p], ta[A], wA.y);
                    dot2(acc[co][p], ta[B], wA.w);
                    dot2(acc[co][p], tb[A], wB.y);
                    dot2(acc[co][p], tb[B], wB.w);
                } else {                      // p odd -> kx0 = 0
                    dot2(acc[co][p], ta[A], wA.x);
                    dot2(acc[co][p], ta[B], wA.z);
                    dot2(acc[co][p], tb[A], wB.x);
                    dot2(acc[co][p], tb[B], wB.z);
                }
            }
        }
    }

    const int oy = ty * 8 + row, oxb = cg * 4;
    float lsum = 0.f;
    #pragma unroll
    for (int co = 0; co < 3; ++co) {
        size_t oi = (((size_t)n * 3 + co) * 128 + oy) * 128 + oxb;
        float4 rf = *(const float4*)&ref[oi];
        float4 st;
        st.x = 1.f / (1.f + __expf(-acc[co][0]));
        st.y = 1.f / (1.f + __expf(-acc[co][1]));
        st.z = 1.f / (1.f + __expf(-acc[co][2]));
        st.w = 1.f / (1.f + __expf(-acc[co][3]));
        *(float4*)&out[oi] = st;
        float d0 = st.x - rf.x, d1 = st.y - rf.y, d2 = st.z - rf.z, d3v = st.w - rf.w;
        lsum += d0 * d0 + d1 * d1 + d2 * d2 + d3v * d3v;
    }
    #pragma unroll
    for (int off = 32; off; off >>= 1) lsum += __shfl_down(lsum, off, 64);
    if ((tid & 63) == 0) atomicAdd(&buckets[blockIdx.x & 255], lsum);
}

__global__ void finalize_kernel(const float* __restrict__ accum, float* __restrict__ out,
                                int out_size) {
    int tid = threadIdx.x;  // 256
    float v  = accum[tid];
    float vq = accum[256 + tid];
    #pragma unroll
    for (int off = 32; off; off >>= 1) {
        v  += __shfl_down(v, off, 64);
        vq += __shfl_down(vq, off, 64);
    }
    __shared__ float s[8];
    if ((tid & 63) == 0) { s[tid >> 6] = v; s[4 + (tid >> 6)] = vq; }
    __syncthreads();
    if (tid == 0) {
        float rt = s[0] + s[1] + s[2] + s[3];
        float qt = s[4] + s[5] + s[6] + s[7];
        out[out_size - 2] = rt / 6291456.f;          // recon_loss
        out[out_size - 1] = 1.25f * qt / 1048576.f;  // vq_loss
    }
}

extern "C" void kernel_launch(void* const* d_in, const int* in_sizes, int n_in,
                              void* d_out, int out_size, void* d_ws, size_t ws_size,
                              hipStream_t stream) {
    const float* x   = (const float*)d_in[0];
    const float* w1  = (const float*)d_in[1];
    const float* b1  = (const float*)d_in[2];
    const float* w2  = (const float*)d_in[3];
    const float* b2  = (const float*)d_in[4];
    const float* w3  = (const float*)d_in[5];
    const float* b3  = (const float*)d_in[6];
    const float* emb = (const float*)d_in[7];
    const float* d1  = (const float*)d_in[8];
    const float* db1 = (const float*)d_in[9];
    const float* d2  = (const float*)d_in[10];
    const float* db2 = (const float*)d_in[11];
    const float* d3  = (const float*)d_in[12];
    const float* db3 = (const float*)d_in[13];

    char* ws = (char*)d_ws;
    u16* h1  = (u16*)(ws + OFF_H1);    // also g2
    u16* h2  = (u16*)(ws + OFF_H2);    // also g1
    u16* zqb = (u16*)(ws + OFF_ZQ);
    u16* w2t = (u16*)(ws + OFF_W2T);
    u16* w3t = (u16*)(ws + OFF_W3T);
    u16* d1t = (u16*)(ws + OFF_D1T);
    u16* d2t = (u16*)(ws + OFF_D2T);
    u32* d3p = (u32*)(ws + OFF_D3P);
    u16* w1t = (u16*)(ws + OFF_W1T);
    u16* xb  = (u16*)(ws + OFF_XB);
    float* acc = (float*)(ws + OFF_ACC);
    float* e2  = (float*)(ws + OFF_E2);
    float* out = (float*)d_out;

    prep_xb<<<528 + 8450, 256, 0, stream>>>(w2, w3, d1, d2, d3, emb, w1, x,
                                            w2t, w3t, d1t, d2t, d3p, w1t, xb, acc, e2);

    // encoder
    conv1_mfma<<<2048, 256, 0, stream>>>(xb, w1t, b1, h1);
    mfma_conv<32, 64, 64, 64, true ><<<1024, 256, 0, stream>>>(h1, w2t, b2, h2);

    // conv3 + fused VQ (no global z round-trip)
    conv3_vq<<<512, 256, 0, stream>>>(h2, w3t, b3, emb, e2, zqb, acc + 256);

    // decoder (g1 reuses h2 space, g2 reuses h1 space)
    u16* g1 = h2; u16* g2 = h1;
    mfma_deconv_wl<32, 64, 16, 16><<<dim3(512, 2), 256, 0, stream>>>(zqb, d1t, db1, g1);
    mfma_deconv_wl<64, 32, 32, 32><<<dim3(1024, 2), 256, 0, stream>>>(g1, d2t, db2, g2);
    deconv3_dot2<<<2048, 256, 0, stream>>>(g2, d3p, db3, out, x, acc);

    finalize_kernel<<<1, 256, 0, stream>>>(acc, out, out_size);
}

// Round 21
// 155.608 us; speedup vs baseline: 1.0125x; 1.0125x over previous
//
#include <hip/hip_runtime.h>
#include <math.h>

#define NEMB 512
#define LAT 32

typedef unsigned short u16;
typedef unsigned int u32;
typedef __attribute__((ext_vector_type(8))) short bf16x8;   // 8 bf16 in 4 VGPRs
typedef __attribute__((ext_vector_type(4))) float f32x4;

__device__ __forceinline__ u16 f2b(float f) {               // fp32 -> bf16 RTNE
    unsigned u = __builtin_bit_cast(unsigned, f);
    return (u16)((u + 0x7fffu + ((u >> 16) & 1u)) >> 16);
}
__device__ __forceinline__ float b2f(u16 h) {
    unsigned u = ((unsigned)h) << 16;
    return __builtin_bit_cast(float, u);
}
// packed bf16-pair dot product: acc += a.lo*b.lo + a.hi*b.hi  (full-rate VALU)
__device__ __forceinline__ void dot2(float& acc, u32 a, u32 b) {
    asm("v_dot2_f32_bf16 %0, %1, %2, %0" : "+v"(acc) : "v"(a), "v"(b));
}

union V16 { uint4 u; u16 s[8]; };
union V8  { uint2 u; u16 s[4]; };

// ---------------- workspace layout (BYTES); ws >= 109 MB (round-1 proven) ----
static const size_t OFF_H1  = 0;          // h1 [128,64,64,32] bf16 (later g2)
static const size_t OFF_H2  = 33554432;   // h2 [128,32,32,64] bf16 (later g1)
static const size_t OFF_Z   = 50331648;   // z  [128,16,16,32] bf16
static const size_t OFF_ZQ  = 52428800;   // zq [128,16,16,32] bf16
static const size_t OFF_W2T = 54525952;   // [16][64][32] bf16
static const size_t OFF_W3T = 54591488;   // [16][32][64] bf16
static const size_t OFF_D1T = 54657024;   // [16][64][32] bf16
static const size_t OFF_D2T = 54722560;   // [16][32][64] bf16
static const size_t OFF_ACC = 54804480;   // f32: [0..255] recon buckets, [256..511] vq buckets
static const size_t OFF_E2  = 54808576;   // f32: per-code ||e||^2 (512 f)
static const size_t OFF_W1T = 54810624;   // [2][32co][32k] bf16 (4 KB)
static const size_t OFF_XB  = 54814720;   // xb [128][130][130][4] bf16 (17.3 MB)
static const size_t OFF_D3P = 72120320;   // u32 [16cp][3co][16kykx] packed pairs (3 KB)

// =================================================================
// prep + xb in ONE dispatch (blocks [0,528) transforms, rest xb)
// =================================================================
__global__ __launch_bounds__(256)
void prep_xb(const float* __restrict__ w2, const float* __restrict__ w3,
             const float* __restrict__ d1, const float* __restrict__ d2,
             const float* __restrict__ d3, const float* __restrict__ emb,
             const float* __restrict__ w1, const float* __restrict__ x,
             u16* __restrict__ w2t, u16* __restrict__ w3t, u16* __restrict__ d1t,
             u16* __restrict__ d2t, u32* __restrict__ d3p, u16* __restrict__ w1t,
             u16* __restrict__ xb,
             float* __restrict__ accum, float* __restrict__ e2) {
    if (blockIdx.x >= 528) {
        int t = (blockIdx.x - 528) * 256 + threadIdx.x;   // 128*130*130
        int xx = t % 130; int t2 = t / 130;
        int yy = t2 % 130; int n = t2 / 130;
        V8 o; o.u = (uint2){0, 0};
        if (xx >= 1 && xx <= 128 && yy >= 1 && yy <= 128) {
            size_t base = ((size_t)n * 3) * 16384 + (size_t)(yy - 1) * 128 + (xx - 1);
            o.s[0] = f2b(x[base]);
            o.s[1] = f2b(x[base + 16384]);
            o.s[2] = f2b(x[base + 32768]);
        }
        *(uint2*)&xb[(size_t)t * 4] = o.u;
        return;
    }
    int t = blockIdx.x * 256 + threadIdx.x;
    if (t < 32768) {                       // w2: conv, CO=64 CI=32 -> [tau][co][ci]
        int ci = t & 31; int t2 = t >> 5; int co = t2 & 63; int tau = t2 >> 6;
        w2t[t] = f2b(w2[((size_t)co * 32 + ci) * 16 + tau]);
    } else if (t < 65536) {                // w3: conv, CO=32 CI=64
        int u = t - 32768;
        int ci = u & 63; int t2 = u >> 6; int co = t2 & 31; int tau = t2 >> 5;
        w3t[u] = f2b(w3[((size_t)co * 64 + ci) * 16 + tau]);
    } else if (t < 98304) {                // d1: deconv, CO=64 CI=32 -> [s][co][ci]
        int u = t - 65536;
        int ci = u & 31; int t2 = u >> 5; int co = t2 & 63; int s = t2 >> 6;
        int ry = (s >> 3) & 1, rx = (s >> 2) & 1, a = (s >> 1) & 1, b = s & 1;
        int ky = ((ry + 1) & 1) + 2 * a, kx = ((rx + 1) & 1) + 2 * b;
        d1t[u] = f2b(d1[((size_t)ci * 64 + co) * 16 + ky * 4 + kx]);
    } else if (t < 131072) {               // d2: deconv, CO=32 CI=64
        int u = t - 98304;
        int ci = u & 63; int t2 = u >> 6; int co = t2 & 31; int s = t2 >> 5;
        int ry = (s >> 3) & 1, rx = (s >> 2) & 1, a = (s >> 1) & 1, b = s & 1;
        int ky = ((ry + 1) & 1) + 2 * a, kx = ((rx + 1) & 1) + 2 * b;
        d2t[u] = f2b(d2[((size_t)ci * 32 + co) * 16 + ky * 4 + kx]);
    } else if (t < 131584) {               // e2
        int u = t - 131072;
        float s = 0.f;
        #pragma unroll
        for (int c = 0; c < LAT; ++c) { float e = emb[u * LAT + c]; s = fmaf(e, e, s); }
        e2[u] = s;
    } else if (t < 132096) {               // zero accumulators
        accum[t - 131584] = 0.f;
    } else if (t < 134144) {               // w1t: [2][32co][32k]
        int u = t - 132096;
        int k = u & 31; int co = (u >> 5) & 31; int c = u >> 10;
        int kyl = k >> 4, kx = (k >> 2) & 3, ch = k & 3;
        w1t[u] = (ch < 3) ? f2b(w1[((size_t)(co * 3 + ch) * 4 + (2 * c + kyl)) * 4 + kx])
                          : (u16)0;
    } else if (t < 134912) {               // d3p: packed ci-pair weights [cp][co][kykx]
        int u = t - 134144;                // 0..767
        int kk = u & 15; int t2 = u >> 4;
        int co = t2 % 3; int cp = t2 / 3;
        u16 lo = f2b(d3[((size_t)(2 * cp) * 3 + co) * 16 + kk]);
        u16 hi = f2b(d3[((size_t)(2 * cp + 1) * 3 + co) * 16 + kk]);
        d3p[u] = (u32)lo | ((u32)hi << 16);
    }
}

// =================================================================
// conv1 MFMA: implicit GEMM, K=64, no LDS, no barrier.
// =================================================================
__global__ __launch_bounds__(256)
void conv1_mfma(const u16* __restrict__ xb, const u16* __restrict__ w1t,
                const float* __restrict__ b1, u16* __restrict__ h1) {
    int bid = blockIdx.x;                       // 128 n x 16 oyb
    const int oyb = bid & 15; const int n = bid >> 4;
    const int tid = threadIdx.x, w = tid >> 6, lane = tid & 63;
    const int l15 = lane & 15, l4 = lane >> 4;
    const int oy = oyb * 4 + w;

    bf16x8 bf[2][2];
    #pragma unroll
    for (int c = 0; c < 2; ++c)
        #pragma unroll
        for (int cf = 0; cf < 2; ++cf)
            bf[c][cf] = *(const bf16x8*)&w1t[((size_t)(c * 32 + cf * 16 + l15)) * 32 + l4 * 8];

    f32x4 acc[4][2];
    #pragma unroll
    for (int f = 0; f < 4; ++f)
        #pragma unroll
        for (int cf = 0; cf < 2; ++cf) {
            float bv = b1[cf * 16 + l15];
            acc[f][cf] = (f32x4){bv, bv, bv, bv};
        }

    #pragma unroll
    for (int c = 0; c < 2; ++c) {
        const int row = 2 * oy + 2 * c + (l4 >> 1);
        #pragma unroll
        for (int f = 0; f < 4; ++f) {
            const int col = 2 * (f * 16 + l15) + (l4 & 1) * 2;
            bf16x8 a = *(const bf16x8*)&xb[(((size_t)n * 130 + row) * 130 + col) * 4];
            acc[f][0] = __builtin_amdgcn_mfma_f32_16x16x32_bf16(a, bf[c][0], acc[f][0], 0, 0, 0);
            acc[f][1] = __builtin_amdgcn_mfma_f32_16x16x32_bf16(a, bf[c][1], acc[f][1], 0, 0, 0);
        }
    }

    #pragma unroll
    for (int f = 0; f < 4; ++f)
        #pragma unroll
        for (int cf = 0; cf < 2; ++cf)
            #pragma unroll
            for (int rg = 0; rg < 4; ++rg) {
                int ox = f * 16 + l4 * 4 + rg;
                h1[(((size_t)n * 64 + oy) * 64 + ox) * 32 + cf * 16 + l15] =
                    f2b(fmaxf(acc[f][cf][rg], 0.f));
            }
}

// =================================================================
// MFMA conv k4s2: NHWC bf16 in/out. unroll 4 on tau.
// =================================================================
template <int CI, int CO, int HI, int WI, bool RELU>
__global__ __launch_bounds__(256)
void mfma_conv(const u16* __restrict__ xin, const u16* __restrict__ wt,
               const float* __restrict__ bias, u16* __restrict__ out) {
    constexpr int HO = HI / 2, WO = WI / 2;
    constexpr int BCOLS = (WO < 32) ? WO : 32;
    constexpr int XC = 2 * BCOLS + 2;
    constexpr int NCOLF = BCOLS / 16, NCOF = CO / 16, NCC = CI / 32;
    constexpr int CPU8 = CI / 8;
    __shared__ u16 sx[10 * XC * CI];

    int bid = blockIdx.x;
    constexpr int NBY = HO / 4, NTX = WO / BCOLS;
    const int tx = bid % NTX; bid /= NTX;
    const int by = bid % NBY; const int n = bid / NBY;
    const int oy0 = by * 4, ox0 = tx * BCOLS;
    const int tid = threadIdx.x, w = tid >> 6, lane = tid & 63;
    const int l15 = lane & 15, l4 = lane >> 4;

    const int iyb = 2 * oy0 - 1, ixb = 2 * ox0 - 1;
    for (int u = tid; u < 10 * XC * CPU8; u += 256) {
        int c8 = u % CPU8; int t2 = u / CPU8;
        int xc = t2 % XC; int r = t2 / XC;
        int iy = iyb + r, ix = ixb + xc;
        uint4 v = {0, 0, 0, 0};
        if (iy >= 0 && iy < HI && ix >= 0 && ix < WI)
            v = *(const uint4*)&xin[(((size_t)n * HI + iy) * WI + ix) * CI + c8 * 8];
        int byte = ((r * XC + xc) * CI + c8 * 8) * 2;
        byte ^= ((xc >> 1) & 7) << 4;
        *(uint4*)&sx[byte >> 1] = v;
    }
    __syncthreads();

    f32x4 acc[NCOLF][NCOF];
    #pragma unroll
    for (int pf = 0; pf < NCOLF; ++pf)
        #pragma unroll
        for (int cf = 0; cf < NCOF; ++cf) {
            float bv = bias[cf * 16 + l15];
            acc[pf][cf] = (f32x4){bv, bv, bv, bv};
        }

    #pragma unroll 4
    for (int tau = 0; tau < 16; ++tau) {
        const int ky = tau >> 2, kx = tau & 3;
        const int r = 2 * w + ky;
        #pragma unroll
        for (int cc = 0; cc < NCC; ++cc) {
            bf16x8 b[NCOF];
            #pragma unroll
            for (int cf = 0; cf < NCOF; ++cf)
                b[cf] = *(const bf16x8*)&wt[((size_t)(tau * CO + cf * 16 + l15)) * CI + cc * 32 + l4 * 8];
            bf16x8 a[NCOLF];
            #pragma unroll
            for (int pf = 0; pf < NCOLF; ++pf) {
                int xc = 2 * (pf * 16 + l15) + kx;
                int byte = ((r * XC + xc) * CI + cc * 32 + l4 * 8) * 2;
                byte ^= ((xc >> 1) & 7) << 4;
                a[pf] = *(const bf16x8*)&sx[byte >> 1];
            }
            #pragma unroll
            for (int pf = 0; pf < NCOLF; ++pf)
                #pragma unroll
                for (int cf = 0; cf < NCOF; ++cf)
                    acc[pf][cf] = __builtin_amdgcn_mfma_f32_16x16x32_bf16(
                        a[pf], b[cf], acc[pf][cf], 0, 0, 0);
        }
    }

    const int oy = oy0 + w;
    #pragma unroll
    for (int pf = 0; pf < NCOLF; ++pf)
        #pragma unroll
        for (int cf = 0; cf < NCOF; ++cf)
            #pragma unroll
            for (int rg = 0; rg < 4; ++rg) {
                int ox = ox0 + pf * 16 + l4 * 4 + rg;
                float v = acc[pf][cf][rg];
                if (RELU) v = fmaxf(v, 0.f);
                out[(((size_t)n * HO + oy) * WO + ox) * CO + cf * 16 + l15] = f2b(v);
            }
}

// =================================================================
// MFMA deconv k4s2, ry = blockIdx.y, WEIGHTS IN LDS (proven r13).
// relu -> bf16 NHWC.
// =================================================================
template <int CI, int CO, int HI, int WI>
__global__ __launch_bounds__(256)
void mfma_deconv_wl(const u16* __restrict__ xin, const u16* __restrict__ wt,
                    const float* __restrict__ bias, u16* __restrict__ out) {
    constexpr int HO = 2 * HI, WO = 2 * WI;
    constexpr int BCOLS = (WI < 32) ? WI : 32;
    constexpr int XC = BCOLS + 2;
    constexpr int NCOLF = BCOLS / 16, NCOF = CO / 16, NCC = CI / 32;
    constexpr int CPU8 = CI / 8;
    __shared__ u16 sx[5 * XC * CI];
    __shared__ u16 swt[8 * CO * CI];          // 32 KB

    const int ry = blockIdx.y;
    int bid = blockIdx.x;
    constexpr int NBY = HI / 4, NTX = WI / BCOLS;
    const int tx = bid % NTX; bid /= NTX;
    const int by = bid % NBY; const int n = bid / NBY;
    const int q0 = by * 4, r0 = tx * BCOLS;
    const int tid = threadIdx.x, w = tid >> 6, lane = tid & 63;
    const int l15 = lane & 15, l4 = lane >> 4;

    const int qb = q0 + ry - 1;
    for (int u = tid; u < 5 * XC * CPU8; u += 256) {
        int c8 = u % CPU8; int t2 = u / CPU8;
        int xc = t2 % XC; int r = t2 / XC;
        int iy = qb + r, ix = r0 - 1 + xc;
        uint4 v = {0, 0, 0, 0};
        if (iy >= 0 && iy < HI && ix >= 0 && ix < WI)
            v = *(const uint4*)&xin[(((size_t)n * HI + iy) * WI + ix) * CI + c8 * 8];
        int byte = ((r * XC + xc) * CI + c8 * 8) * 2;
        byte ^= (xc & 7) << 4;
        *(uint4*)&sx[byte >> 1] = v;
    }
    const u16* wts = wt + (size_t)(ry * 8) * CO * CI;
    for (int u = tid; u < 8 * CO * CPU8; u += 256) {
        int c8 = u % CPU8; int t2 = u / CPU8;
        int co = t2 % CO; int l = t2 / CO;
        uint4 v = *(const uint4*)&wts[((size_t)l * CO + co) * CI + c8 * 8];
        int byte = ((l * CO + co) * CI + c8 * 8) * 2;
        byte ^= (co & 7) << 4;
        *(uint4*)&swt[byte >> 1] = v;
    }
    __syncthreads();

    f32x4 acc[2][NCOLF][NCOF];
    #pragma unroll
    for (int rx = 0; rx < 2; ++rx)
        #pragma unroll
        for (int pf = 0; pf < NCOLF; ++pf)
            #pragma unroll
            for (int cf = 0; cf < NCOF; ++cf) {
                float bv = bias[cf * 16 + l15];
                acc[rx][pf][cf] = (f32x4){bv, bv, bv, bv};
            }

    #pragma unroll
    for (int rx = 0; rx < 2; ++rx) {
        #pragma unroll
        for (int tap = 0; tap < 4; ++tap) {
            const int a_ = tap >> 1, b_ = tap & 1;
            const int r = w + 1 - a_;
            const int l = rx * 4 + tap;
            #pragma unroll
            for (int cc = 0; cc < NCC; ++cc) {
                bf16x8 b[NCOF];
                #pragma unroll
                for (int cf = 0; cf < NCOF; ++cf) {
                    int co = cf * 16 + l15;
                    int byte = (((l * CO + co) * CI + cc * 32 + l4 * 8) * 2) ^ ((co & 7) << 4);
                    b[cf] = *(const bf16x8*)((const char*)swt + byte);
                }
                bf16x8 a[NCOLF];
                #pragma unroll
                for (int pf = 0; pf < NCOLF; ++pf) {
                    int xc = pf * 16 + l15 + rx - b_ + 1;
                    int byte = ((r * XC + xc) * CI + cc * 32 + l4 * 8) * 2;
                    byte ^= (xc & 7) << 4;
                    a[pf] = *(const bf16x8*)&sx[byte >> 1];
                }
                #pragma unroll
                for (int pf = 0; pf < NCOLF; ++pf)
                    #pragma unroll
                    for (int cf = 0; cf < NCOF; ++cf)
                        acc[rx][pf][cf] = __builtin_amdgcn_mfma_f32_16x16x32_bf16(
                            a[pf], b[cf], acc[rx][pf][cf], 0, 0, 0);
            }
        }
    }

    const int oy = 2 * (q0 + w) + ry;
    #pragma unroll
    for (int rx = 0; rx < 2; ++rx)
        #pragma unroll
        for (int pf = 0; pf < NCOLF; ++pf)
            #pragma unroll
            for (int cf = 0; cf < NCOF; ++cf)
                #pragma unroll
                for (int rg = 0; rg < 4; ++rg) {
                    int ox = 2 * (r0 + pf * 16 + l4 * 4 + rg) + rx;
                    float v = fmaxf(acc[rx][pf][cf][rg], 0.f);
                    out[(((size_t)n * HO + oy) * WO + ox) * CO + cf * 16 + l15] = f2b(v);
                }
}

// =================================================================
// deconv3 dot2 (r17 best): taps from LDS ci-pair planes; packed
// weights broadcast from a 3 KB LDS buffer. PPT=4, parity-grouped.
// =================================================================
__global__ __launch_bounds__(256)
void deconv3_dot2(const u16* __restrict__ g2, const u32* __restrict__ d3p,
                  const float* __restrict__ db3, float* __restrict__ out,
                  const float* __restrict__ ref, float* __restrict__ buckets) {
    __shared__ u32 sxp[16 * 412];         // 26.4 KB (16 ci-pair planes)
    __shared__ u32 sw[768];               // 3 KB packed weights [cp][co][kykx]
    int bid = blockIdx.x;
    const int ty = bid & 15; const int n = bid >> 4;
    const int tid = threadIdx.x;
    const int w = tid >> 6, lane = tid & 63;
    const int row = (w & 1) + 4 * (w >> 1) + 2 * (lane >> 5);   // parity-grouped
    const int cg = lane & 31;                  // 32 col groups x 4 px

    const int iy_org = ty * 4 - 1;

    for (int u = tid; u < 6 * 66 * 4; u += 256) {
        int c8 = u & 3; int pos = u >> 2;
        int col = pos % 66; int r = pos / 66;
        int iy = iy_org + r, ix = col - 1;
        uint4 v = {0, 0, 0, 0};
        if (iy >= 0 && iy < 64 && ix >= 0 && ix < 64)
            v = *(const uint4*)&g2[(((size_t)n * 64 + iy) * 64 + ix) * 32 + c8 * 8];
        int base = r * 68 + col;
        sxp[(c8 * 4 + 0) * 412 + base] = v.x;
        sxp[(c8 * 4 + 1) * 412 + base] = v.y;
        sxp[(c8 * 4 + 2) * 412 + base] = v.z;
        sxp[(c8 * 4 + 3) * 412 + base] = v.w;
    }
    for (int l = tid; l < 768; l += 256) sw[l] = d3p[l];
    __syncthreads();

    const int ky0 = (row + 1) & 1;               // wave-uniform
    const int iyA = ((row + 1 - ky0) >> 1) + 1;
    const int iyB = iyA - 1;
    const int q = cg * 2;

    float acc[3][4];
    #pragma unroll
    for (int co = 0; co < 3; ++co) {
        float b = db3[co];
        #pragma unroll
        for (int p = 0; p < 4; ++p) acc[co][p] = b;
    }

    #pragma unroll 1
    for (int c2 = 0; c2 < 16; ++c2) {
        uint4 hA = *(const uint4*)&sxp[c2 * 412 + iyA * 68 + q];
        uint4 hB = *(const uint4*)&sxp[c2 * 412 + iyB * 68 + q];
        u32 ta[4] = {hA.x, hA.y, hA.z, hA.w};
        u32 tb[4] = {hB.x, hB.y, hB.z, hB.w};
        #pragma unroll
        for (int co = 0; co < 3; ++co) {
            uint4 wA = *(const uint4*)&sw[(c2 * 3 + co) * 16 + ky0 * 4];        // broadcast
            uint4 wB = *(const uint4*)&sw[(c2 * 3 + co) * 16 + (ky0 + 2) * 4];  // broadcast
            #pragma unroll
            for (int p = 0; p < 4; ++p) {
                const int A = (p + 3) >> 1;
                const int B = (p + 1) >> 1;
                if (((p + 1) & 1) == 1) {     // p even -> kx0 = 1
                    dot2(acc[co][p], ta[A], wA.y);
                    dot2(acc[co][p], ta[B], wA.w);
                    dot2(acc[co][p], tb[A], wB.y);
                    dot2(acc[co][p], tb[B], wB.w);
                } else {                      // p odd -> kx0 = 0
                    dot2(acc[co][p], ta[A], wA.x);
                    dot2(acc[co][p], ta[B], wA.z);
                    dot2(acc[co][p], tb[A], wB.x);
                    dot2(acc[co][p], tb[B], wB.z);
                }
            }
        }
    }

    const int oy = ty * 8 + row, oxb = cg * 4;
    float lsum = 0.f;
    #pragma unroll
    for (int co = 0; co < 3; ++co) {
        size_t oi = (((size_t)n * 3 + co) * 128 + oy) * 128 + oxb;
        float4 rf = *(const float4*)&ref[oi];
        float4 st;
        st.x = 1.f / (1.f + __expf(-acc[co][0]));
        st.y = 1.f / (1.f + __expf(-acc[co][1]));
        st.z = 1.f / (1.f + __expf(-acc[co][2]));
        st.w = 1.f / (1.f + __expf(-acc[co][3]));
        *(float4*)&out[oi] = st;
        float d0 = st.x - rf.x, d1 = st.y - rf.y, d2 = st.z - rf.z, d3v = st.w - rf.w;
        lsum += d0 * d0 + d1 * d1 + d2 * d2 + d3v * d3v;
    }
    #pragma unroll
    for (int off = 32; off; off >>= 1) lsum += __shfl_down(lsum, off, 64);
    if ((tid & 63) == 0) atomicAdd(&buckets[blockIdx.x & 255], lsum);
}

// =================================================================
// MFMA VQ: distances via z @ emb^T, wave-parallel argmin + fused gather.
// =================================================================
__global__ __launch_bounds__(256)
void vq_mfma(const u16* __restrict__ z, const float* __restrict__ emb,
             const float* __restrict__ e2g, u16* __restrict__ zq,
             float* __restrict__ vq_buckets) {
    __shared__ u16 semb[NEMB * LAT];   // 32 KB, XOR-swizzled [code][k]
    __shared__ float se2[NEMB];        // 2 KB
    const int tid = threadIdx.x;

    for (int u = tid; u < 2048; u += 256) {
        int code = u >> 2, seg = u & 3;
        const float4* ep = (const float4*)&emb[code * 32 + seg * 8];
        float4 e0 = ep[0], e1 = ep[1];
        V16 o;
        o.s[0] = f2b(e0.x); o.s[1] = f2b(e0.y); o.s[2] = f2b(e0.z); o.s[3] = f2b(e0.w);
        o.s[4] = f2b(e1.x); o.s[5] = f2b(e1.y); o.s[6] = f2b(e1.z); o.s[7] = f2b(e1.w);
        int byte = (code * 64 + seg * 16) ^ ((code & 7) << 4);
        *(uint4*)((char*)semb + byte) = o.u;
    }
    if (tid < NEMB) se2[tid] = e2g[tid];
    __syncthreads();

    const int w = tid >> 6, lane = tid & 63;
    const int l15 = lane & 15, l4 = lane >> 4;
    const int rowbase = blockIdx.x * 64 + w * 16;

    bf16x8 a = *(const bf16x8*)&z[(size_t)(rowbase + l15) * LAT + l4 * 8];

    float best[4] = {1e30f, 1e30f, 1e30f, 1e30f};
    int   bidx[4] = {0, 0, 0, 0};
    #pragma unroll
    for (int f = 0; f < 32; ++f) {
        int byteb = ((f * 16 + l15) * 64 + l4 * 16) ^ ((l15 & 7) << 4);
        bf16x8 bfrag = *(const bf16x8*)((const char*)semb + byteb);
        f32x4 s = {0.f, 0.f, 0.f, 0.f};
        s = __builtin_amdgcn_mfma_f32_16x16x32_bf16(a, bfrag, s, 0, 0, 0);
        float e2c = se2[f * 16 + l15];
        int cidx = f * 16 + l15;
        #pragma unroll
        for (int j = 0; j < 4; ++j) {
            float d = fmaf(s[j], -2.f, e2c);
            bool lt = d < best[j];
            best[j] = lt ? d : best[j];
            bidx[j] = lt ? cidx : bidx[j];
        }
    }
    #pragma unroll
    for (int m = 1; m < 16; m <<= 1) {
        #pragma unroll
        for (int j = 0; j < 4; ++j) {
            float ob = __shfl_xor(best[j], m, 64);
            int   oi = __shfl_xor(bidx[j], m, 64);
            bool take = (ob < best[j]) || (ob == best[j] && oi < bidx[j]);
            best[j] = take ? ob : best[j];
            bidx[j] = take ? oi : bidx[j];
        }
    }
    const int r = lane >> 2;
    const int j0 = r & 3;
    int k = (j0 == 0) ? bidx[0] : (j0 == 1) ? bidx[1] : (j0 == 2) ? bidx[2] : bidx[3];
    const int seg = lane & 3;
    const float4* ep = (const float4*)&emb[k * LAT + seg * 8];
    float4 e0 = ep[0], e1 = ep[1];
    float ev[8] = {e0.x, e0.y, e0.z, e0.w, e1.x, e1.y, e1.z, e1.w};
    size_t zoff = (size_t)(rowbase + r) * LAT + seg * 8;
    V16 zr; zr.u = *(const uint4*)&z[zoff];
    V16 o;
    float local = 0.f;
    #pragma unroll
    for (int jj = 0; jj < 8; ++jj) {
        float dd = ev[jj] - b2f(zr.s[jj]);
        local = fmaf(dd, dd, local);
        o.s[jj] = f2b(ev[jj]);
    }
    *(uint4*)&zq[zoff] = o.u;
    #pragma unroll
    for (int off = 32; off; off >>= 1) local += __shfl_down(local, off, 64);
    if (lane == 0) atomicAdd(&vq_buckets[blockIdx.x & 255], local);
}

__global__ void finalize_kernel(const float* __restrict__ accum, float* __restrict__ out,
                                int out_size) {
    int tid = threadIdx.x;  // 256
    float v  = accum[tid];
    float vq = accum[256 + tid];
    #pragma unroll
    for (int off = 32; off; off >>= 1) {
        v  += __shfl_down(v, off, 64);
        vq += __shfl_down(vq, off, 64);
    }
    __shared__ float s[8];
    if ((tid & 63) == 0) { s[tid >> 6] = v; s[4 + (tid >> 6)] = vq; }
    __syncthreads();
    if (tid == 0) {
        float rt = s[0] + s[1] + s[2] + s[3];
        float qt = s[4] + s[5] + s[6] + s[7];
        out[out_size - 2] = rt / 6291456.f;          // recon_loss
        out[out_size - 1] = 1.25f * qt / 1048576.f;  // vq_loss
    }
}

extern "C" void kernel_launch(void* const* d_in, const int* in_sizes, int n_in,
                              void* d_out, int out_size, void* d_ws, size_t ws_size,
                              hipStream_t stream) {
    const float* x   = (const float*)d_in[0];
    const float* w1  = (const float*)d_in[1];
    const float* b1  = (const float*)d_in[2];
    const float* w2  = (const float*)d_in[3];
    const float* b2  = (const float*)d_in[4];
    const float* w3  = (const float*)d_in[5];
    const float* b3  = (const float*)d_in[6];
    const float* emb = (const float*)d_in[7];
    const float* d1  = (const float*)d_in[8];
    const float* db1 = (const float*)d_in[9];
    const float* d2  = (const float*)d_in[10];
    const float* db2 = (const float*)d_in[11];
    const float* d3  = (const float*)d_in[12];
    const float* db3 = (const float*)d_in[13];

    char* ws = (char*)d_ws;
    u16* h1  = (u16*)(ws + OFF_H1);    // also g2
    u16* h2  = (u16*)(ws + OFF_H2);    // also g1
    u16* zb  = (u16*)(ws + OFF_Z);
    u16* zqb = (u16*)(ws + OFF_ZQ);
    u16* w2t = (u16*)(ws + OFF_W2T);
    u16* w3t = (u16*)(ws + OFF_W3T);
    u16* d1t = (u16*)(ws + OFF_D1T);
    u16* d2t = (u16*)(ws + OFF_D2T);
    u32* d3p = (u32*)(ws + OFF_D3P);
    u16* w1t = (u16*)(ws + OFF_W1T);
    u16* xb  = (u16*)(ws + OFF_XB);
    float* acc = (float*)(ws + OFF_ACC);
    float* e2  = (float*)(ws + OFF_E2);
    float* out = (float*)d_out;

    prep_xb<<<528 + 8450, 256, 0, stream>>>(w2, w3, d1, d2, d3, emb, w1, x,
                                            w2t, w3t, d1t, d2t, d3p, w1t, xb, acc, e2);

    // encoder
    conv1_mfma<<<2048, 256, 0, stream>>>(xb, w1t, b1, h1);
    mfma_conv<32, 64, 64, 64, true ><<<1024, 256, 0, stream>>>(h1, w2t, b2, h2);
    mfma_conv<64, 32, 32, 32, false><<<512, 256, 0, stream>>>(h2, w3t, b3, zb);

    // vector quantization
    vq_mfma<<<512, 256, 0, stream>>>(zb, emb, e2, zqb, acc + 256);

    // decoder (g1 reuses h2 space, g2 reuses h1 space)
    u16* g1 = h2; u16* g2 = h1;
    mfma_deconv_wl<32, 64, 16, 16><<<dim3(512, 2), 256, 0, stream>>>(zqb, d1t, db1, g1);
    mfma_deconv_wl<64, 32, 32, 32><<<dim3(1024, 2), 256, 0, stream>>>(g1, d2t, db2, g2);
    deconv3_dot2<<<2048, 256, 0, stream>>>(g2, d3p, db3, out, x, acc);

    finalize_kernel<<<1, 256, 0, stream>>>(acc, out, out_size);
}